// Round 3
// baseline (145.481 us; speedup 1.0000x reference)
//
#include <hip/hip_runtime.h>
#include <hip/hip_bf16.h>
#include <stdint.h>

#define T_DIM 8192
#define B_DIM 8
#define D_DIM 512
#define O_DIM 512

typedef __attribute__((ext_vector_type(4))) float f32x4;
typedef __attribute__((ext_vector_type(8))) short short8;
typedef __attribute__((ext_vector_type(4))) unsigned short us4;

__device__ __forceinline__ unsigned short f2bf(float f) {
  union { float f; uint32_t u; } v; v.f = f;
  uint32_t u = v.u + 0x7FFFu + ((v.u >> 16) & 1u);   // RNE
  return (unsigned short)(u >> 16);
}

__device__ __forceinline__ uint32_t cvtpk(float a, float b) {
  uint32_t r;
  asm("v_cvt_pk_bf16_f32 %0, %1, %2" : "=v"(r) : "v"(a), "v"(b));
  return r;
}

__device__ __forceinline__ void gload_lds16(const void* g, void* l) {
  __builtin_amdgcn_global_load_lds(
      (const __attribute__((address_space(1))) void*)g,
      (__attribute__((address_space(3))) void*)l, 16, 0, 0);
}

__device__ __forceinline__ float clip_lam(const float* decay) {
  return fminf(fmaxf(decay[0], 0.5f), 0.999f);
}

// ---------------------------------------------------------------------------
// Pass 1: h_avg = mean_b x  AND  xbf = bf16(x)  (fused, x read once)
__global__ void mean_cvt_kernel(const float* __restrict__ x, float* __restrict__ havg,
                                unsigned short* __restrict__ xbf) {
  int idx = blockIdx.x * 256 + threadIdx.x;           // over T*D/4
  const f32x4* x4 = (const f32x4*)x;
  us4* xb4 = (us4*)xbf;
  const size_t stride = (size_t)T_DIM * D_DIM / 4;
  f32x4 s = {0.f, 0.f, 0.f, 0.f};
#pragma unroll
  for (int b = 0; b < B_DIM; ++b) {
    f32x4 v = x4[(size_t)b * stride + idx];
    s += v;
    us4 o;
#pragma unroll
    for (int j = 0; j < 4; ++j) o[j] = f2bf(v[j]);
    xb4[(size_t)b * stride + idx] = o;
  }
  s *= 0.125f;
  ((f32x4*)havg)[idx] = s;
}

// Plain mean (fallback path when ws is too small for xbf)
__global__ void mean_kernel(const float* __restrict__ x, float* __restrict__ havg) {
  int idx = blockIdx.x * 256 + threadIdx.x;
  const f32x4* x4 = (const f32x4*)x;
  const size_t stride = (size_t)T_DIM * D_DIM / 4;
  f32x4 s = {0.f, 0.f, 0.f, 0.f};
#pragma unroll
  for (int b = 0; b < B_DIM; ++b) s += x4[(size_t)b * stride + idx];
  s *= 0.125f;
  ((f32x4*)havg)[idx] = s;
}

// ---------------------------------------------------------------------------
// Pass 2: W (2D x O, f32, [k][n]) -> Wt bf16 n-major: Wt[h][n][k]=W[h*512+k][n]
__global__ void wconv_kernel(const float* __restrict__ W, unsigned short* __restrict__ Wt) {
  __shared__ float tile[64][65];
  int bk = blockIdx.x >> 3;
  int bn = blockIdx.x & 7;
  int tr = threadIdx.x >> 4;
  int tc = threadIdx.x & 15;
#pragma unroll
  for (int i = 0; i < 4; ++i) {
    int row = i * 16 + tr;
    f32x4 v = *(const f32x4*)&W[(size_t)(bk * 64 + row) * O_DIM + bn * 64 + tc * 4];
#pragma unroll
    for (int j = 0; j < 4; ++j) tile[row][tc * 4 + j] = v[j];
  }
  __syncthreads();
#pragma unroll
  for (int i = 0; i < 4; ++i) {
    int nl = i * 16 + tr;
    us4 o;
#pragma unroll
    for (int j = 0; j < 4; ++j) o[j] = f2bf(tile[tc * 4 + j][nl]);
    int kg = bk * 64 + tc * 4;
    int h = kg >> 9;
    int k = kg & 511;
    *(us4*)&Wt[(size_t)h * (512 * 512) + (size_t)(bn * 64 + nl) * 512 + k] = o;
  }
}

// ---------------------------------------------------------------------------
// Exact 3-pass chunked EMA scan. CHUNK=128, NCHUNK=64.
#define CHUNK 128
#define NCHUNK (T_DIM / CHUNK)

__global__ void scanA_kernel(float* __restrict__ havg, const float* __restrict__ decay) {
  int chunk = blockIdx.x >> 1;
  int d = ((blockIdx.x & 1) << 8) + threadIdx.x;
  float lam = clip_lam(decay);
  float om = 1.0f - lam;
  size_t base = (size_t)chunk * CHUNK * D_DIM + d;
  float cur[16], nxt[16];
#pragma unroll
  for (int i = 0; i < 16; ++i) cur[i] = havg[base + (size_t)i * D_DIM];
  float s = 0.f;
  for (int blk = 0; blk < 8; ++blk) {
    if (blk < 7) {
#pragma unroll
      for (int i = 0; i < 16; ++i)
        nxt[i] = havg[base + (size_t)((blk + 1) * 16 + i) * D_DIM];
    }
#pragma unroll
    for (int i = 0; i < 16; ++i) {
      s = lam * s + om * cur[i];
      havg[base + (size_t)(blk * 16 + i) * D_DIM] = s;
    }
#pragma unroll
    for (int i = 0; i < 16; ++i) cur[i] = nxt[i];
  }
}

__global__ void scanB_kernel(const float* __restrict__ havg, const float* __restrict__ decay,
                             float* __restrict__ carry) {
  int d = blockIdx.x * 256 + threadIdx.x;
  float lam = clip_lam(decay);
  float l2 = lam * lam;
  float l4 = l2 * l2;
  float l8 = l4 * l4;
  float l16 = l8 * l8;
  float l32 = l16 * l16;
  float l64 = l32 * l32;
  float l128 = l64 * l64;
  float e[NCHUNK];
#pragma unroll
  for (int c = 0; c < NCHUNK; ++c)
    e[c] = havg[((size_t)c * CHUNK + CHUNK - 1) * D_DIM + d];
  float s = 0.f;
#pragma unroll
  for (int c = 0; c < NCHUNK; ++c) {
    s = l128 * s + e[c];
    carry[c * D_DIM + d] = s;
  }
}

__global__ void scanC_kernel(const float* __restrict__ havg, const float* __restrict__ carry,
                             const float* __restrict__ decay, unsigned short* __restrict__ st) {
  int idx = blockIdx.x * 256 + threadIdx.x;
  int t = idx >> 7;
  int d4 = idx & 127;
  int c = t >> 7;
  int k = t & 127;
  float lam = clip_lam(decay);
  float w = exp2f((float)(k + 1) * __log2f(lam));
  f32x4 p = ((const f32x4*)havg)[idx];
  f32x4 cin = {0.f, 0.f, 0.f, 0.f};
  if (c > 0) cin = ((const f32x4*)carry)[(size_t)(c - 1) * 128 + d4];
  us4 o;
#pragma unroll
  for (int j = 0; j < 4; ++j) o[j] = f2bf(p[j] + w * cin[j]);
  ((us4*)st)[idx] = o;
}

// ---------------------------------------------------------------------------
// bf16 GEMM: C[M][512] = A[M][512] @ Bt^T + epilogue. 128x128, BK=32, 4 waves.
// LDS tiles [128 rows][32 bf16]; 16B-octet XOR swizzle: stored octet
// mb = o ^ perm(row), perm(row)=(row>>1)&3, applied at the GLOBAL source
// (gload_lds writes linearly) and inverted at the fragment read.
template <bool ADD_SBAR>
__global__ __launch_bounds__(256, 2)
void gemm128bf(const unsigned short* __restrict__ A, const unsigned short* __restrict__ Bt,
               const float* __restrict__ extra, float* __restrict__ C) {
  __shared__ __align__(16) char smem[16384];
  unsigned short* Bs = (unsigned short*)(smem + 8192);

  int nwg = gridDim.x;
  int bid = blockIdx.x;
  int swz = (bid & 7) * (nwg >> 3) + (bid >> 3);
  int tm = swz >> 2, tn = swz & 3;
  int brow = tm << 7, bcol = tn << 7;

  int tid = threadIdx.x;
  int wave = tid >> 6, lane = tid & 63;
  int wr = (wave >> 1) << 6, wc = (wave & 1) << 6;
  const int lr = lane & 15, lkb = lane >> 4;

  // staging-side swizzle: lane l covers (row = q*16 + l>>2, memBlock = l&3);
  // logical octet at that slot = (l&3) ^ perm(row), perm = ((l>>3)&3)
  const int srow = lane >> 2;
  const int soct = ((lane & 3) ^ ((lane >> 3) & 3)) << 3;   // element offset in row
  // read-side: perm(row)= (lr>>1)&3 for all fragment rows (wr,m*16 are mult. of 8... of 16)
  const int pm = (lr >> 1) & 3;

  f32x4 acc[4][4];
#pragma unroll
  for (int m = 0; m < 4; ++m)
#pragma unroll
    for (int n = 0; n < 4; ++n) acc[m][n] = (f32x4){0.f, 0.f, 0.f, 0.f};

  for (int kt = 0; kt < 512 / 32; ++kt) {
    int k0 = kt << 5;
#pragma unroll
    for (int it = 0; it < 2; ++it) {
      int q = (it << 2) + wave;                 // 0..7, 1 KiB chunks (16 rows)
      int row = (q << 4) + srow;
      gload_lds16(A + (size_t)(brow + row) * 512 + k0 + soct, smem + (q << 10));
      gload_lds16(Bt + (size_t)(bcol + row) * 512 + k0 + soct, (char*)Bs + (q << 10));
    }
    __syncthreads();

    const unsigned short* As = (const unsigned short*)smem;
    short8 af[4], bfr[4];
#pragma unroll
    for (int m = 0; m < 4; ++m)
      af[m] = *(const short8*)(As + (size_t)(wr + (m << 4) + lr) * 32 + ((lkb ^ pm) << 3));
#pragma unroll
    for (int n = 0; n < 4; ++n)
      bfr[n] = *(const short8*)(Bs + (size_t)(wc + (n << 4) + lr) * 32 + ((lkb ^ pm) << 3));

#pragma unroll
    for (int m = 0; m < 4; ++m)
#pragma unroll
      for (int n = 0; n < 4; ++n)
        acc[m][n] = __builtin_amdgcn_mfma_f32_16x16x32_bf16(af[m], bfr[n], acc[m][n], 0, 0, 0);
    __syncthreads();
  }

#pragma unroll
  for (int m = 0; m < 4; ++m) {
    int row0 = brow + wr + (m << 4) + ((lane >> 4) << 2);
#pragma unroll
    for (int n = 0; n < 4; ++n) {
      int col = bcol + wc + (n << 4) + lr;
#pragma unroll
      for (int j = 0; j < 4; ++j) {
        int row = row0 + j;
        float v = acc[m][n][j];
        if constexpr (ADD_SBAR)
          v += extra[(size_t)(row & (T_DIM - 1)) * O_DIM + col];
        else
          v += extra[col];
        C[(size_t)row * O_DIM + col] = v;
      }
    }
  }
}

// ---------------------------------------------------------------------------
// Fallback f32-A GEMM (used only if ws too small for xbf). Same as R2 kernel.
__global__ __launch_bounds__(256, 2)
void gemm128f32(const float* __restrict__ Ag, const unsigned short* __restrict__ Bt,
                const float* __restrict__ extra, float* __restrict__ C) {
  __shared__ __align__(16) char smem[16384 + 8192];
  unsigned short* Bs = (unsigned short*)(smem + 16384);

  int nwg = gridDim.x;
  int bid = blockIdx.x;
  int swz = (bid & 7) * (nwg >> 3) + (bid >> 3);
  int tm = swz >> 2, tn = swz & 3;
  int brow = tm << 7, bcol = tn << 7;

  int tid = threadIdx.x;
  int wave = tid >> 6, lane = tid & 63;
  int wr = (wave >> 1) << 6, wc = (wave & 1) << 6;
  const int lr = lane & 15, lkb = lane >> 4;

  f32x4 acc[4][4];
#pragma unroll
  for (int m = 0; m < 4; ++m)
#pragma unroll
    for (int n = 0; n < 4; ++n) acc[m][n] = (f32x4){0.f, 0.f, 0.f, 0.f};

  for (int kt = 0; kt < 512 / 32; ++kt) {
    int k0 = kt << 5;
#pragma unroll
    for (int it = 0; it < 4; ++it) {
      int q = (it << 2) + wave;
      int row = (q << 3) + (lane >> 3);
      int kc = ((lane & 7) ^ (lane >> 3)) << 2;
      gload_lds16(Ag + (size_t)(brow + row) * 512 + k0 + kc, smem + (q << 10));
    }
#pragma unroll
    for (int it = 0; it < 2; ++it) {
      int q = (it << 2) + wave;
      int n = (q << 4) + (lane >> 2);
      int kc = (lane & 3) << 3;
      gload_lds16(Bt + (size_t)(bcol + n) * 512 + k0 + kc, (char*)Bs + (q << 10));
    }
    __syncthreads();

    short8 af[4], bfr[4];
    const float* As = (const float*)smem;
#pragma unroll
    for (int m = 0; m < 4; ++m) {
      int row = wr + (m << 4) + lr;
      int r7 = row & 7;
      int b0 = lkb << 1;
      f32x4 lo = *(const f32x4*)(As + row * 32 + ((b0 ^ r7) << 2));
      f32x4 hi = *(const f32x4*)(As + row * 32 + (((b0 + 1) ^ r7) << 2));
      union { short8 s; uint32_t u[4]; } t;
      t.u[0] = cvtpk(lo[0], lo[1]); t.u[1] = cvtpk(lo[2], lo[3]);
      t.u[2] = cvtpk(hi[0], hi[1]); t.u[3] = cvtpk(hi[2], hi[3]);
      af[m] = t.s;
    }
#pragma unroll
    for (int n = 0; n < 4; ++n)
      bfr[n] = *(const short8*)(Bs + (size_t)(wc + (n << 4) + lr) * 32 + (lkb << 3));

#pragma unroll
    for (int m = 0; m < 4; ++m)
#pragma unroll
      for (int n = 0; n < 4; ++n)
        acc[m][n] = __builtin_amdgcn_mfma_f32_16x16x32_bf16(af[m], bfr[n], acc[m][n], 0, 0, 0);
    __syncthreads();
  }

#pragma unroll
  for (int m = 0; m < 4; ++m) {
    int row0 = brow + wr + (m << 4) + ((lane >> 4) << 2);
#pragma unroll
    for (int n = 0; n < 4; ++n) {
      int col = bcol + wc + (n << 4) + lr;
#pragma unroll
      for (int j = 0; j < 4; ++j) {
        int row = row0 + j;
        C[(size_t)row * O_DIM + col] =
            acc[m][n][j] + extra[(size_t)(row & (T_DIM - 1)) * O_DIM + col];
      }
    }
  }
}

// ---------------------------------------------------------------------------
extern "C" void kernel_launch(void* const* d_in, const int* in_sizes, int n_in,
                              void* d_out, int out_size, void* d_ws, size_t ws_size,
                              hipStream_t stream) {
  (void)in_sizes; (void)n_in; (void)out_size;
  const float* x     = (const float*)d_in[0];   // [8][8192][512]
  const float* W     = (const float*)d_in[1];   // [1024][512]
  const float* bias  = (const float*)d_in[2];   // [512]
  const float* decay = (const float*)d_in[3];   // [1]
  float* out = (float*)d_out;                   // [8][8192][512]

  char* ws = (char*)d_ws;
  size_t off = 0;
  float*          havg  = (float*)(ws + off);          off += 16777216;  // 16 MiB
  unsigned short* st    = (unsigned short*)(ws + off); off += 8388608;   //  8 MiB
  unsigned short* Wt    = (unsigned short*)(ws + off); off += 1048576;   //  1 MiB
  float*          sbar  = (float*)(ws + off);          off += 16777216;  // 16 MiB
  float*          carry = (float*)(ws + off);          off += 131072;    // 128 KiB
  unsigned short* xbf   = (unsigned short*)(ws + off); off += (size_t)B_DIM * T_DIM * D_DIM * 2; // 64 MiB
  const bool use_bf = (ws_size >= off);

  if (use_bf) {
    mean_cvt_kernel<<<T_DIM * D_DIM / 4 / 256, 256, 0, stream>>>(x, havg, xbf);
  } else {
    mean_kernel<<<T_DIM * D_DIM / 4 / 256, 256, 0, stream>>>(x, havg);
  }
  wconv_kernel<<<128, 256, 0, stream>>>(W, Wt);
  scanA_kernel<<<NCHUNK * 2, 256, 0, stream>>>(havg, decay);
  scanB_kernel<<<2, 256, 0, stream>>>(havg, decay, carry);
  scanC_kernel<<<T_DIM * D_DIM / 4 / 256, 256, 0, stream>>>(havg, carry, decay, st);
  gemm128bf<false><<<(T_DIM / 128) * 4, 256, 0, stream>>>(st, Wt + 512 * 512, bias, sbar);
  if (use_bf) {
    gemm128bf<true><<<(B_DIM * T_DIM / 128) * 4, 256, 0, stream>>>(xbf, Wt, sbar, out);
  } else {
    gemm128f32<<<(B_DIM * T_DIM / 128) * 4, 256, 0, stream>>>(x, Wt, sbar, out);
  }
}

// Round 5
// 143.333 us; speedup vs baseline: 1.0150x; 1.0150x over previous
//
#include <hip/hip_runtime.h>
#include <hip/hip_bf16.h>
#include <stdint.h>

#define T_DIM 8192
#define B_DIM 8
#define D_DIM 512
#define O_DIM 512

typedef __attribute__((ext_vector_type(4))) float f32x4;
typedef __attribute__((ext_vector_type(8))) short short8;
typedef __attribute__((ext_vector_type(4))) unsigned short us4;

__device__ __forceinline__ unsigned short f2bf(float f) {
  union { float f; uint32_t u; } v; v.f = f;
  uint32_t u = v.u + 0x7FFFu + ((v.u >> 16) & 1u);   // RNE
  return (unsigned short)(u >> 16);
}

__device__ __forceinline__ uint32_t cvtpk(float a, float b) {
  uint32_t r;
  asm("v_cvt_pk_bf16_f32 %0, %1, %2" : "=v"(r) : "v"(a), "v"(b));
  return r;
}

__device__ __forceinline__ void gload_lds16(const void* g, void* l) {
  __builtin_amdgcn_global_load_lds(
      (const __attribute__((address_space(1))) void*)g,
      (__attribute__((address_space(3))) void*)l, 16, 0, 0);
}

__device__ __forceinline__ float clip_lam(const float* decay) {
  return fminf(fmaxf(decay[0], 0.5f), 0.999f);
}

// ---------------------------------------------------------------------------
// Pass 1: h_avg = mean_b x  AND  xbf = bf16(x)  (fused, x read once)
__global__ void mean_cvt_kernel(const float* __restrict__ x, float* __restrict__ havg,
                                unsigned short* __restrict__ xbf) {
  int idx = blockIdx.x * 256 + threadIdx.x;           // over T*D/4
  const f32x4* x4 = (const f32x4*)x;
  us4* xb4 = (us4*)xbf;
  const size_t stride = (size_t)T_DIM * D_DIM / 4;
  f32x4 s = {0.f, 0.f, 0.f, 0.f};
#pragma unroll
  for (int b = 0; b < B_DIM; ++b) {
    f32x4 v = x4[(size_t)b * stride + idx];
    s += v;
    us4 o;
#pragma unroll
    for (int j = 0; j < 4; ++j) o[j] = f2bf(v[j]);
    xb4[(size_t)b * stride + idx] = o;
  }
  s *= 0.125f;
  ((f32x4*)havg)[idx] = s;
}

__global__ void mean_kernel(const float* __restrict__ x, float* __restrict__ havg) {
  int idx = blockIdx.x * 256 + threadIdx.x;
  const f32x4* x4 = (const f32x4*)x;
  const size_t stride = (size_t)T_DIM * D_DIM / 4;
  f32x4 s = {0.f, 0.f, 0.f, 0.f};
#pragma unroll
  for (int b = 0; b < B_DIM; ++b) s += x4[(size_t)b * stride + idx];
  s *= 0.125f;
  ((f32x4*)havg)[idx] = s;
}

// ---------------------------------------------------------------------------
// Pass 2: W (2D x O, f32, [k][n]) -> Wt bf16 n-major: Wt[h][n][k]=W[h*512+k][n]
__global__ void wconv_kernel(const float* __restrict__ W, unsigned short* __restrict__ Wt) {
  __shared__ float tile[64][65];
  int bk = blockIdx.x >> 3;
  int bn = blockIdx.x & 7;
  int tr = threadIdx.x >> 4;
  int tc = threadIdx.x & 15;
#pragma unroll
  for (int i = 0; i < 4; ++i) {
    int row = i * 16 + tr;
    f32x4 v = *(const f32x4*)&W[(size_t)(bk * 64 + row) * O_DIM + bn * 64 + tc * 4];
#pragma unroll
    for (int j = 0; j < 4; ++j) tile[row][tc * 4 + j] = v[j];
  }
  __syncthreads();
#pragma unroll
  for (int i = 0; i < 4; ++i) {
    int nl = i * 16 + tr;
    us4 o;
#pragma unroll
    for (int j = 0; j < 4; ++j) o[j] = f2bf(tile[tc * 4 + j][nl]);
    int kg = bk * 64 + tc * 4;
    int h = kg >> 9;
    int k = kg & 511;
    *(us4*)&Wt[(size_t)h * (512 * 512) + (size_t)(bn * 64 + nl) * 512 + k] = o;
  }
}

// ---------------------------------------------------------------------------
// Exact 3-pass chunked EMA scan. CHUNK=128, NCHUNK=64.
#define CHUNK 128
#define NCHUNK (T_DIM / CHUNK)

__global__ void scanA_kernel(float* __restrict__ havg, const float* __restrict__ decay) {
  int chunk = blockIdx.x >> 1;
  int d = ((blockIdx.x & 1) << 8) + threadIdx.x;
  float lam = clip_lam(decay);
  float om = 1.0f - lam;
  size_t base = (size_t)chunk * CHUNK * D_DIM + d;
  float cur[16], nxt[16];
#pragma unroll
  for (int i = 0; i < 16; ++i) cur[i] = havg[base + (size_t)i * D_DIM];
  float s = 0.f;
  for (int blk = 0; blk < 8; ++blk) {
    if (blk < 7) {
#pragma unroll
      for (int i = 0; i < 16; ++i)
        nxt[i] = havg[base + (size_t)((blk + 1) * 16 + i) * D_DIM];
    }
#pragma unroll
    for (int i = 0; i < 16; ++i) {
      s = lam * s + om * cur[i];
      havg[base + (size_t)(blk * 16 + i) * D_DIM] = s;
    }
#pragma unroll
    for (int i = 0; i < 16; ++i) cur[i] = nxt[i];
  }
}

__global__ void scanB_kernel(const float* __restrict__ havg, const float* __restrict__ decay,
                             float* __restrict__ carry) {
  int d = blockIdx.x * 256 + threadIdx.x;
  float lam = clip_lam(decay);
  float l2 = lam * lam;
  float l4 = l2 * l2;
  float l8 = l4 * l4;
  float l16 = l8 * l8;
  float l32 = l16 * l16;
  float l64 = l32 * l32;
  float l128 = l64 * l64;
  float e[NCHUNK];
#pragma unroll
  for (int c = 0; c < NCHUNK; ++c)
    e[c] = havg[((size_t)c * CHUNK + CHUNK - 1) * D_DIM + d];
  float s = 0.f;
#pragma unroll
  for (int c = 0; c < NCHUNK; ++c) {
    s = l128 * s + e[c];
    carry[c * D_DIM + d] = s;
  }
}

__global__ void scanC_kernel(const float* __restrict__ havg, const float* __restrict__ carry,
                             const float* __restrict__ decay, unsigned short* __restrict__ st) {
  int idx = blockIdx.x * 256 + threadIdx.x;
  int t = idx >> 7;
  int d4 = idx & 127;
  int c = t >> 7;
  int k = t & 127;
  float lam = clip_lam(decay);
  float w = exp2f((float)(k + 1) * __log2f(lam));
  f32x4 p = ((const f32x4*)havg)[idx];
  f32x4 cin = {0.f, 0.f, 0.f, 0.f};
  if (c > 0) cin = ((const f32x4*)carry)[(size_t)(c - 1) * 128 + d4];
  us4 o;
#pragma unroll
  for (int j = 0; j < 4; ++j) o[j] = f2bf(p[j] + w * cin[j]);
  ((us4*)st)[idx] = o;
}

// ---------------------------------------------------------------------------
// bf16 GEMM, double-buffered (stage(t+1) BEFORE compute(t), one barrier/tile).
// 128x128 tile, BK=32, 4 waves. 16B-octet XOR swizzle on both LDS tiles.
// Epilogue: per-wave LDS transpose -> dwordx4 stores (+ vectorized extra add).
template <bool ADD_SBAR>
__global__ __launch_bounds__(256, 4)
void gemm128bf(const unsigned short* __restrict__ A, const unsigned short* __restrict__ Bt,
               const float* __restrict__ extra, float* __restrict__ C) {
  __shared__ __align__(16) char smem[2][16384];   // [buf][A 8KB | B 8KB]

  int nwg = gridDim.x;
  int bid = blockIdx.x;
  int swz = (bid & 7) * (nwg >> 3) + (bid >> 3);
  int tm = swz >> 2, tn = swz & 3;
  int brow = tm << 7, bcol = tn << 7;

  int tid = threadIdx.x;
  int wave = tid >> 6, lane = tid & 63;
  int wr = (wave >> 1) << 6, wc = (wave & 1) << 6;
  const int lr = lane & 15, lkb = lane >> 4;

  // staging-side: lane covers (row-local = lane>>2, mem-octet = lane&3);
  // swizzled global octet = (lane&3) ^ ((lane>>3)&3)
  const int srow = lane >> 2;
  const int soct = ((lane & 3) ^ ((lane >> 3) & 3)) << 3;
  const int pm = (lr >> 1) & 3;                  // read-side inverse perm

  f32x4 acc[4][4];
#pragma unroll
  for (int m = 0; m < 4; ++m)
#pragma unroll
    for (int n = 0; n < 4; ++n) acc[m][n] = (f32x4){0.f, 0.f, 0.f, 0.f};

  const size_t arow0 = (size_t)(brow + (wave << 4) + srow) * 512 + soct;
  const size_t brow0 = (size_t)(bcol + (wave << 4) + srow) * 512 + soct;

  // chunk q = it*4+wave covers tile rows [q*16, q*16+16): global element
  // offset for it is it*64 rows * 512 = it<<15.  (R4 bug: had it<<12.)
#define STAGE(buf, kt)                                                          \
  {                                                                             \
    int k0_ = (kt) << 5;                                                        \
    _Pragma("unroll")                                                           \
    for (int it = 0; it < 2; ++it) {                                            \
      int q = (it << 2) + wave;                                                 \
      gload_lds16(A + arow0 + (size_t)(it << 15) + k0_, &smem[buf][q << 10]);   \
      gload_lds16(Bt + brow0 + (size_t)(it << 15) + k0_,                        \
                  &smem[buf][8192 + (q << 10)]);                                \
    }                                                                           \
  }

  STAGE(0, 0);
  __syncthreads();                                // drains vmcnt(0): buf0 ready

  for (int kt = 0; kt < 16; ++kt) {
    int cur = kt & 1;
    if (kt < 15) STAGE(cur ^ 1, kt + 1);          // prefetch next tile

    const unsigned short* As = (const unsigned short*)&smem[cur][0];
    const unsigned short* Bs = (const unsigned short*)&smem[cur][8192];
    short8 af[4], bfr[4];
#pragma unroll
    for (int m = 0; m < 4; ++m)
      af[m] = *(const short8*)(As + (size_t)(wr + (m << 4) + lr) * 32 + ((lkb ^ pm) << 3));
#pragma unroll
    for (int n = 0; n < 4; ++n)
      bfr[n] = *(const short8*)(Bs + (size_t)(wc + (n << 4) + lr) * 32 + ((lkb ^ pm) << 3));

#pragma unroll
    for (int m = 0; m < 4; ++m)
#pragma unroll
      for (int n = 0; n < 4; ++n)
        acc[m][n] = __builtin_amdgcn_mfma_f32_16x16x32_bf16(af[m], bfr[n], acc[m][n], 0, 0, 0);

    __syncthreads();                              // reads of cur done + stage landed
  }
#undef STAGE

  // ---- epilogue: per-wave LDS transpose, 16 rows at a time ([16][68] f32) ----
  float* tp = (float*)&smem[0][0] + (size_t)wave * 2048;   // disjoint 8KB per wave
#pragma unroll
  for (int m = 0; m < 4; ++m) {
#pragma unroll
    for (int n = 0; n < 4; ++n)
#pragma unroll
      for (int j = 0; j < 4; ++j)
        tp[((lkb << 2) + j) * 68 + (n << 4) + lr] = acc[m][n][j];
    __syncthreads();                              // writes visible (block fence)
#pragma unroll
    for (int p = 0; p < 4; ++p) {
      int rl = (p << 2) + (lane >> 4);            // 0..15
      int c0 = (lane & 15) << 2;                  // 0..60
      f32x4 v = *(const f32x4*)(tp + rl * 68 + c0);
      int row = brow + wr + (m << 4) + rl;
      int col = bcol + wc + c0;
      f32x4 e;
      if constexpr (ADD_SBAR)
        e = *(const f32x4*)&extra[(size_t)(row & (T_DIM - 1)) * O_DIM + col];
      else
        e = *(const f32x4*)&extra[col];
      v += e;
      *(f32x4*)&C[(size_t)row * O_DIM + col] = v;
    }
    __syncthreads();                              // before next m overwrites region
  }
}

// ---------------------------------------------------------------------------
// Fallback f32-A GEMM (only if ws too small for xbf). Proven R2 version.
__global__ __launch_bounds__(256, 2)
void gemm128f32(const float* __restrict__ Ag, const unsigned short* __restrict__ Bt,
                const float* __restrict__ extra, float* __restrict__ C) {
  __shared__ __align__(16) char smem[16384 + 8192];
  unsigned short* Bs = (unsigned short*)(smem + 16384);

  int nwg = gridDim.x;
  int bid = blockIdx.x;
  int swz = (bid & 7) * (nwg >> 3) + (bid >> 3);
  int tm = swz >> 2, tn = swz & 3;
  int brow = tm << 7, bcol = tn << 7;

  int tid = threadIdx.x;
  int wave = tid >> 6, lane = tid & 63;
  int wr = (wave >> 1) << 6, wc = (wave & 1) << 6;
  const int lr = lane & 15, lkb = lane >> 4;

  f32x4 acc[4][4];
#pragma unroll
  for (int m = 0; m < 4; ++m)
#pragma unroll
    for (int n = 0; n < 4; ++n) acc[m][n] = (f32x4){0.f, 0.f, 0.f, 0.f};

  for (int kt = 0; kt < 512 / 32; ++kt) {
    int k0 = kt << 5;
#pragma unroll
    for (int it = 0; it < 4; ++it) {
      int q = (it << 2) + wave;
      int row = (q << 3) + (lane >> 3);
      int kc = ((lane & 7) ^ (lane >> 3)) << 2;
      gload_lds16(Ag + (size_t)(brow + row) * 512 + k0 + kc, smem + (q << 10));
    }
#pragma unroll
    for (int it = 0; it < 2; ++it) {
      int q = (it << 2) + wave;
      int n = (q << 4) + (lane >> 2);
      int kc = (lane & 3) << 3;
      gload_lds16(Bt + (size_t)(bcol + n) * 512 + k0 + kc, (char*)Bs + (q << 10));
    }
    __syncthreads();

    short8 af[4], bfr[4];
    const float* As = (const float*)smem;
#pragma unroll
    for (int m = 0; m < 4; ++m) {
      int row = wr + (m << 4) + lr;
      int r7 = row & 7;
      int b0 = lkb << 1;
      f32x4 lo = *(const f32x4*)(As + row * 32 + ((b0 ^ r7) << 2));
      f32x4 hi = *(const f32x4*)(As + row * 32 + (((b0 + 1) ^ r7) << 2));
      union { short8 s; uint32_t u[4]; } t;
      t.u[0] = cvtpk(lo[0], lo[1]); t.u[1] = cvtpk(lo[2], lo[3]);
      t.u[2] = cvtpk(hi[0], hi[1]); t.u[3] = cvtpk(hi[2], hi[3]);
      af[m] = t.s;
    }
#pragma unroll
    for (int n = 0; n < 4; ++n)
      bfr[n] = *(const short8*)(Bs + (size_t)(wc + (n << 4) + lr) * 32 + (lkb << 3));

#pragma unroll
    for (int m = 0; m < 4; ++m)
#pragma unroll
      for (int n = 0; n < 4; ++n)
        acc[m][n] = __builtin_amdgcn_mfma_f32_16x16x32_bf16(af[m], bfr[n], acc[m][n], 0, 0, 0);
    __syncthreads();
  }

#pragma unroll
  for (int m = 0; m < 4; ++m) {
    int row0 = brow + wr + (m << 4) + ((lane >> 4) << 2);
#pragma unroll
    for (int n = 0; n < 4; ++n) {
      int col = bcol + wc + (n << 4) + lr;
#pragma unroll
      for (int j = 0; j < 4; ++j) {
        int row = row0 + j;
        C[(size_t)row * O_DIM + col] =
            acc[m][n][j] + extra[(size_t)(row & (T_DIM - 1)) * O_DIM + col];
      }
    }
  }
}

// ---------------------------------------------------------------------------
extern "C" void kernel_launch(void* const* d_in, const int* in_sizes, int n_in,
                              void* d_out, int out_size, void* d_ws, size_t ws_size,
                              hipStream_t stream) {
  (void)in_sizes; (void)n_in; (void)out_size;
  const float* x     = (const float*)d_in[0];   // [8][8192][512]
  const float* W     = (const float*)d_in[1];   // [1024][512]
  const float* bias  = (const float*)d_in[2];   // [512]
  const float* decay = (const float*)d_in[3];   // [1]
  float* out = (float*)d_out;                   // [8][8192][512]

  char* ws = (char*)d_ws;
  size_t off = 0;
  float*          havg  = (float*)(ws + off);          off += 16777216;  // 16 MiB
  unsigned short* st    = (unsigned short*)(ws + off); off += 8388608;   //  8 MiB
  unsigned short* Wt    = (unsigned short*)(ws + off); off += 1048576;   //  1 MiB
  float*          sbar  = (float*)(ws + off);          off += 16777216;  // 16 MiB
  float*          carry = (float*)(ws + off);          off += 131072;    // 128 KiB
  unsigned short* xbf   = (unsigned short*)(ws + off); off += (size_t)B_DIM * T_DIM * D_DIM * 2; // 64 MiB
  const bool use_bf = (ws_size >= off);

  if (use_bf) {
    mean_cvt_kernel<<<T_DIM * D_DIM / 4 / 256, 256, 0, stream>>>(x, havg, xbf);
  } else {
    mean_kernel<<<T_DIM * D_DIM / 4 / 256, 256, 0, stream>>>(x, havg);
  }
  wconv_kernel<<<128, 256, 0, stream>>>(W, Wt);
  scanA_kernel<<<NCHUNK * 2, 256, 0, stream>>>(havg, decay);
  scanB_kernel<<<2, 256, 0, stream>>>(havg, decay, carry);
  scanC_kernel<<<T_DIM * D_DIM / 4 / 256, 256, 0, stream>>>(havg, carry, decay, st);
  gemm128bf<false><<<(T_DIM / 128) * 4, 256, 0, stream>>>(st, Wt + 512 * 512, bias, sbar);
  if (use_bf) {
    gemm128bf<true><<<(B_DIM * T_DIM / 128) * 4, 256, 0, stream>>>(xbf, Wt, sbar, out);
  } else {
    gemm128f32<<<(B_DIM * T_DIM / 128) * 4, 256, 0, stream>>>(x, Wt, sbar, out);
  }
}

// Round 6
// 128.564 us; speedup vs baseline: 1.1316x; 1.1149x over previous
//
#include <hip/hip_runtime.h>
#include <hip/hip_bf16.h>
#include <stdint.h>

#define T_DIM 8192
#define B_DIM 8
#define D_DIM 512
#define O_DIM 512

typedef __attribute__((ext_vector_type(4))) float f32x4;
typedef __attribute__((ext_vector_type(8))) short short8;
typedef __attribute__((ext_vector_type(4))) unsigned short us4;

__device__ __forceinline__ unsigned short f2bf(float f) {
  union { float f; uint32_t u; } v; v.f = f;
  uint32_t u = v.u + 0x7FFFu + ((v.u >> 16) & 1u);   // RNE
  return (unsigned short)(u >> 16);
}

__device__ __forceinline__ uint32_t cvtpk(float a, float b) {
  uint32_t r;
  asm("v_cvt_pk_bf16_f32 %0, %1, %2" : "=v"(r) : "v"(a), "v"(b));
  return r;
}

__device__ __forceinline__ void gload_lds16(const void* g, void* l) {
  __builtin_amdgcn_global_load_lds(
      (const __attribute__((address_space(1))) void*)g,
      (__attribute__((address_space(3))) void*)l, 16, 0, 0);
}

__device__ __forceinline__ float clip_lam(const float* decay) {
  return fminf(fmaxf(decay[0], 0.5f), 0.999f);
}

// ---------------------------------------------------------------------------
// Pass 1: h_avg[t][d] = mean_b x[b][t][d].  Batched loads (8 in flight).
__global__ void mean_kernel(const float* __restrict__ x, float* __restrict__ havg) {
  int idx = blockIdx.x * 256 + threadIdx.x;           // over T*D/4
  const f32x4* x4 = (const f32x4*)x;
  const size_t stride = (size_t)T_DIM * D_DIM / 4;
  f32x4 v[8];
#pragma unroll
  for (int b = 0; b < B_DIM; ++b) v[b] = x4[(size_t)b * stride + idx];
  f32x4 s = ((v[0] + v[1]) + (v[2] + v[3])) + ((v[4] + v[5]) + (v[6] + v[7]));
  s *= 0.125f;
  ((f32x4*)havg)[idx] = s;
}

// ---------------------------------------------------------------------------
// Pass 2: W (2D x O, f32, [k][n]) -> Wt bf16 n-major: Wt[h][n][k]=W[h*512+k][n]
__global__ void wconv_kernel(const float* __restrict__ W, unsigned short* __restrict__ Wt) {
  __shared__ float tile[64][65];
  int bk = blockIdx.x >> 3;
  int bn = blockIdx.x & 7;
  int tr = threadIdx.x >> 4;
  int tc = threadIdx.x & 15;
#pragma unroll
  for (int i = 0; i < 4; ++i) {
    int row = i * 16 + tr;
    f32x4 v = *(const f32x4*)&W[(size_t)(bk * 64 + row) * O_DIM + bn * 64 + tc * 4];
#pragma unroll
    for (int j = 0; j < 4; ++j) tile[row][tc * 4 + j] = v[j];
  }
  __syncthreads();
#pragma unroll
  for (int i = 0; i < 4; ++i) {
    int nl = i * 16 + tr;
    us4 o;
#pragma unroll
    for (int j = 0; j < 4; ++j) o[j] = f2bf(tile[tc * 4 + j][nl]);
    int kg = bk * 64 + tc * 4;
    int h = kg >> 9;
    int k = kg & 511;
    *(us4*)&Wt[(size_t)h * (512 * 512) + (size_t)(bn * 64 + nl) * 512 + k] = o;
  }
}

// ---------------------------------------------------------------------------
// Exact 3-pass chunked EMA scan. CHUNK=128, NCHUNK=64.
#define CHUNK 128
#define NCHUNK (T_DIM / CHUNK)

__global__ void scanA_kernel(float* __restrict__ havg, const float* __restrict__ decay) {
  int chunk = blockIdx.x >> 1;
  int d = ((blockIdx.x & 1) << 8) + threadIdx.x;
  float lam = clip_lam(decay);
  float om = 1.0f - lam;
  size_t base = (size_t)chunk * CHUNK * D_DIM + d;
  float cur[16], nxt[16];
#pragma unroll
  for (int i = 0; i < 16; ++i) cur[i] = havg[base + (size_t)i * D_DIM];
  float s = 0.f;
  for (int blk = 0; blk < 8; ++blk) {
    if (blk < 7) {
#pragma unroll
      for (int i = 0; i < 16; ++i)
        nxt[i] = havg[base + (size_t)((blk + 1) * 16 + i) * D_DIM];
    }
#pragma unroll
    for (int i = 0; i < 16; ++i) {
      s = lam * s + om * cur[i];
      havg[base + (size_t)(blk * 16 + i) * D_DIM] = s;
    }
#pragma unroll
    for (int i = 0; i < 16; ++i) cur[i] = nxt[i];
  }
}

__global__ void scanB_kernel(const float* __restrict__ havg, const float* __restrict__ decay,
                             float* __restrict__ carry) {
  int d = blockIdx.x * 256 + threadIdx.x;
  float lam = clip_lam(decay);
  float l2 = lam * lam;
  float l4 = l2 * l2;
  float l8 = l4 * l4;
  float l16 = l8 * l8;
  float l32 = l16 * l16;
  float l64 = l32 * l32;
  float l128 = l64 * l64;
  float e[NCHUNK];
#pragma unroll
  for (int c = 0; c < NCHUNK; ++c)
    e[c] = havg[((size_t)c * CHUNK + CHUNK - 1) * D_DIM + d];
  float s = 0.f;
#pragma unroll
  for (int c = 0; c < NCHUNK; ++c) {
    s = l128 * s + e[c];
    carry[c * D_DIM + d] = s;
  }
}

__global__ void scanC_kernel(const float* __restrict__ havg, const float* __restrict__ carry,
                             const float* __restrict__ decay, unsigned short* __restrict__ st) {
  int idx = blockIdx.x * 256 + threadIdx.x;
  int t = idx >> 7;
  int d4 = idx & 127;
  int c = t >> 7;
  int k = t & 127;
  float lam = clip_lam(decay);
  float w = exp2f((float)(k + 1) * __log2f(lam));
  f32x4 p = ((const f32x4*)havg)[idx];
  f32x4 cin = {0.f, 0.f, 0.f, 0.f};
  if (c > 0) cin = ((const f32x4*)carry)[(size_t)(c - 1) * 128 + d4];
  us4 o;
#pragma unroll
  for (int j = 0; j < 4; ++j) o[j] = f2bf(p[j] + w * cin[j]);
  ((us4*)st)[idx] = o;
}

// ---------------------------------------------------------------------------
// GEMM: C[M][512] = A[M][512] @ Bt^T + epilogue. 128x128 tile, BK=32, 4 waves.
// Double-buffered with COUNTED vmcnt (T4): two raw s_barriers per K-step,
// next tile's loads stay in flight across both.  AF32: A staged as raw f32
// (16B-block XOR swizzle), converted at fragment read via v_cvt_pk_bf16_f32.
template <bool AF32, bool ADD_SBAR>
__global__ __launch_bounds__(256, AF32 ? 3 : 4)
void gemm128(const void* __restrict__ Av, const unsigned short* __restrict__ Bt,
             const float* __restrict__ extra, float* __restrict__ C) {
  constexpr int ABYTES = AF32 ? 16384 : 8192;
  constexpr int BUFB = ABYTES + 8192;
  __shared__ __align__(16) char smem[2][BUFB];

  int nwg = gridDim.x;
  int bid = blockIdx.x;
  int swz = (bid & 7) * (nwg >> 3) + (bid >> 3);
  int tm = swz >> 2, tn = swz & 3;
  int brow = tm << 7, bcol = tn << 7;

  int tid = threadIdx.x;
  int wave = tid >> 6, lane = tid & 63;
  int wr = (wave >> 1) << 6, wc = (wave & 1) << 6;
  const int lr = lane & 15, lkb = lane >> 4;

  // bf16 staging swizzle (16B octets): logical octet = slot ^ ((row>>1)&3)
  const int soct = ((lane & 3) ^ ((lane >> 3) & 3)) << 3;   // bf16 elements
  const int pm = (lr >> 1) & 3;                             // read-side inverse
  // f32 staging swizzle (16B blocks): logical block = slot ^ (row&7)
  const int kcA = ((lane & 7) ^ (lane >> 3)) << 2;          // f32 elements

  // global base addresses (element units)
  const size_t a_base = AF32
      ? (size_t)(brow + (wave << 3) + (lane >> 3)) * 512 + kcA
      : (size_t)(brow + (wave << 4) + (lane >> 2)) * 512 + soct;
  const size_t b_base = (size_t)(bcol + (wave << 4) + (lane >> 2)) * 512 + soct;

  f32x4 acc[4][4];
#pragma unroll
  for (int m = 0; m < 4; ++m)
#pragma unroll
    for (int n = 0; n < 4; ++n) acc[m][n] = (f32x4){0.f, 0.f, 0.f, 0.f};

  // A chunks: f32: q=it*4+wave covers 8 rows (it: +32 rows = it<<14 elems);
  //           bf16: q=it*4+wave covers 16 rows (it: +64 rows = it<<15 elems).
  // B chunks: q=it*4+wave covers 16 rows (it<<15 elems).
#define STAGE(buf, kt_)                                                        \
  {                                                                            \
    int k0_ = (kt_) << 5;                                                      \
    if constexpr (AF32) {                                                      \
      const float* Ag = (const float*)Av;                                      \
      _Pragma("unroll")                                                        \
      for (int it = 0; it < 4; ++it)                                           \
        gload_lds16(Ag + a_base + (size_t)(it << 14) + k0_,                    \
                    &smem[buf][(((it << 2) + wave) << 10)]);                   \
    } else {                                                                   \
      const unsigned short* Ag = (const unsigned short*)Av;                    \
      _Pragma("unroll")                                                        \
      for (int it = 0; it < 2; ++it)                                           \
        gload_lds16(Ag + a_base + (size_t)(it << 15) + k0_,                    \
                    &smem[buf][(((it << 2) + wave) << 10)]);                   \
    }                                                                          \
    _Pragma("unroll")                                                          \
    for (int it = 0; it < 2; ++it)                                             \
      gload_lds16(Bt + b_base + (size_t)(it << 15) + k0_,                      \
                  &smem[buf][ABYTES + (((it << 2) + wave) << 10)]);            \
  }

  STAGE(0, 0);                                   // 6 (f32) / 4 (bf16) in flight

#pragma unroll
  for (int kt = 0; kt < 16; ++kt) {
    const int cur = kt & 1;
    if (kt < 15) {
      STAGE(cur ^ 1, kt + 1);                    // +N new loads in flight
      if constexpr (AF32)
        asm volatile("s_waitcnt vmcnt(6)" ::: "memory");   // cur's 6 done
      else
        asm volatile("s_waitcnt vmcnt(4)" ::: "memory");   // cur's 4 done
    } else {
      asm volatile("s_waitcnt vmcnt(0)" ::: "memory");
    }
    __builtin_amdgcn_s_barrier();                // all waves: cur ready
    __builtin_amdgcn_sched_barrier(0);

    short8 af[4], bfr[4];
    if constexpr (AF32) {
      const float* As = (const float*)&smem[cur][0];
#pragma unroll
      for (int m = 0; m < 4; ++m) {
        int row = wr + (m << 4) + lr;
        int r7 = row & 7;
        int b0 = lkb << 1;
        f32x4 lo = *(const f32x4*)(As + row * 32 + ((b0 ^ r7) << 2));
        f32x4 hi = *(const f32x4*)(As + row * 32 + (((b0 + 1) ^ r7) << 2));
        union { short8 s; uint32_t u[4]; } t;
        t.u[0] = cvtpk(lo[0], lo[1]); t.u[1] = cvtpk(lo[2], lo[3]);
        t.u[2] = cvtpk(hi[0], hi[1]); t.u[3] = cvtpk(hi[2], hi[3]);
        af[m] = t.s;
      }
    } else {
      const unsigned short* As = (const unsigned short*)&smem[cur][0];
#pragma unroll
      for (int m = 0; m < 4; ++m)
        af[m] = *(const short8*)(As + (size_t)(wr + (m << 4) + lr) * 32 + ((lkb ^ pm) << 3));
    }
    const unsigned short* Bs = (const unsigned short*)&smem[cur][ABYTES];
#pragma unroll
    for (int n = 0; n < 4; ++n)
      bfr[n] = *(const short8*)(Bs + (size_t)(wc + (n << 4) + lr) * 32 + ((lkb ^ pm) << 3));

#pragma unroll
    for (int m = 0; m < 4; ++m)
#pragma unroll
      for (int n = 0; n < 4; ++n)
        acc[m][n] = __builtin_amdgcn_mfma_f32_16x16x32_bf16(af[m], bfr[n], acc[m][n], 0, 0, 0);

    __builtin_amdgcn_sched_barrier(0);
    __builtin_amdgcn_s_barrier();                // all reads of cur done ->
  }                                              // next STAGE may overwrite it
#undef STAGE

  // ---- epilogue: per-wave LDS transpose, 16 rows at a time ([16][68] f32) ----
  float* tp = (float*)&smem[0][0] + (size_t)wave * 2048;   // disjoint 8KB/wave
#pragma unroll
  for (int m = 0; m < 4; ++m) {
#pragma unroll
    for (int n = 0; n < 4; ++n)
#pragma unroll
      for (int j = 0; j < 4; ++j)
        tp[((lkb << 2) + j) * 68 + (n << 4) + lr] = acc[m][n][j];
    __syncthreads();
#pragma unroll
    for (int p = 0; p < 4; ++p) {
      int rl = (p << 2) + (lane >> 4);            // 0..15
      int c0 = (lane & 15) << 2;                  // 0..60
      f32x4 v = *(const f32x4*)(tp + rl * 68 + c0);
      int row = brow + wr + (m << 4) + rl;
      int col = bcol + wc + c0;
      f32x4 e;
      if constexpr (ADD_SBAR)
        e = *(const f32x4*)&extra[(size_t)(row & (T_DIM - 1)) * O_DIM + col];
      else
        e = *(const f32x4*)&extra[col];
      v += e;
      *(f32x4*)&C[(size_t)row * O_DIM + col] = v;
    }
    __syncthreads();
  }
}

// ---------------------------------------------------------------------------
extern "C" void kernel_launch(void* const* d_in, const int* in_sizes, int n_in,
                              void* d_out, int out_size, void* d_ws, size_t ws_size,
                              hipStream_t stream) {
  (void)in_sizes; (void)n_in; (void)out_size; (void)ws_size;
  const float* x     = (const float*)d_in[0];   // [8][8192][512]
  const float* W     = (const float*)d_in[1];   // [1024][512]
  const float* bias  = (const float*)d_in[2];   // [512]
  const float* decay = (const float*)d_in[3];   // [1]
  float* out = (float*)d_out;                   // [8][8192][512]

  char* ws = (char*)d_ws;
  size_t off = 0;
  float*          havg  = (float*)(ws + off);          off += 16777216;  // 16 MiB
  unsigned short* st    = (unsigned short*)(ws + off); off += 8388608;   //  8 MiB
  unsigned short* Wt    = (unsigned short*)(ws + off); off += 1048576;   //  1 MiB
  float*          sbar  = (float*)(ws + off);          off += 16777216;  // 16 MiB
  float*          carry = (float*)(ws + off);          off += 131072;    // 128 KiB

  mean_kernel<<<T_DIM * D_DIM / 4 / 256, 256, 0, stream>>>(x, havg);
  wconv_kernel<<<128, 256, 0, stream>>>(W, Wt);
  scanA_kernel<<<NCHUNK * 2, 256, 0, stream>>>(havg, decay);
  scanB_kernel<<<2, 256, 0, stream>>>(havg, decay, carry);
  scanC_kernel<<<T_DIM * D_DIM / 4 / 256, 256, 0, stream>>>(havg, carry, decay, st);
  // sbar[t][o] = states @ W_s + b   (M=8192, bf16 A)
  gemm128<false, false><<<(T_DIM / 128) * 4, 256, 0, stream>>>(st, Wt + 512 * 512, bias, sbar);
  // out[b*T+t][o] = x @ W_h + sbar[t][o]   (M=65536, f32 A staged raw)
  gemm128<true, true><<<(B_DIM * T_DIM / 128) * 4, 256, 0, stream>>>(x, Wt, sbar, out);
}